// Round 7
// baseline (449.385 us; speedup 1.0000x reference)
//
#include <hip/hip_runtime.h>
#include <stdint.h>

typedef unsigned short u16;
typedef __attribute__((ext_vector_type(8))) short bf16x8;   // 8 bf16 in 4 VGPRs
typedef __attribute__((ext_vector_type(4))) float f32x4;

#define B_   16
#define C_   256
#define HW_  4096
#define HID_ 128
#define NBLK 256

__device__ __forceinline__ float b2f(u16 u) {
  union { uint32_t i; float f; } v; v.i = ((uint32_t)u) << 16; return v.f;
}
__device__ __forceinline__ u16 f2b(float f) {
  union { float f; uint32_t i; } v; v.f = f;
  uint32_t r = (v.i + 0x7FFFu + ((v.i >> 16) & 1u)) >> 16;
  return (u16)r;
}

// Zero the grid-barrier state (ws is re-poisoned 0xAA before every call).
__global__ void init_kernel(unsigned* bar) {
  if (threadIdx.x < 8) bar[threadIdx.x] = 0u;
}

// Sense-reversing grid barrier. All NBLK blocks are co-resident
// (1 block/CU: 512 thr, 119KB LDS), so spinning is deadlock-free.
__device__ __forceinline__ void grid_barrier(unsigned* bar) {
  __syncthreads();
  if (threadIdx.x == 0) {
    __threadfence();
    unsigned g = __hip_atomic_load(&bar[1], __ATOMIC_RELAXED, __HIP_MEMORY_SCOPE_AGENT);
    unsigned a = __hip_atomic_fetch_add(&bar[0], 1u, __ATOMIC_ACQ_REL, __HIP_MEMORY_SCOPE_AGENT);
    if (a == NBLK - 1) {
      __hip_atomic_store(&bar[0], 0u, __ATOMIC_RELAXED, __HIP_MEMORY_SCOPE_AGENT);
      __hip_atomic_store(&bar[1], g + 1u, __ATOMIC_RELEASE, __HIP_MEMORY_SCOPE_AGENT);
    } else {
      while (__hip_atomic_load(&bar[1], __ATOMIC_ACQUIRE, __HIP_MEMORY_SCOPE_AGENT) == g) {
        __builtin_amdgcn_s_sleep(1);
      }
    }
  }
  __syncthreads();
}

// ---------------------------------------------------------------------------
// Persistent mega-kernel: 256 blocks x 512 threads (8 waves), 5 phases.
// ---------------------------------------------------------------------------
__global__ __launch_bounds__(512, 2) void mega_kernel(
    const float* __restrict__ x, const float* __restrict__ gnw,
    const float* __restrict__ gnb, const float* __restrict__ qkvw,
    const float* __restrict__ qkvb, const float* __restrict__ outw,
    const float* __restrict__ outb, float* __restrict__ out,
    unsigned* bar, float* scale, float* shiftv, u16* cqkvw,
    u16* xn_t, u16* kv, u16* q_t, float* ctxg, float* sbuf)
{
  __shared__ __align__(16) char smem_raw[119296];
  int t = threadIdx.x;
  int blk = blockIdx.x;

  // ===== Phase 0: convert qkv_w -> bf16; zero ctx+s; GroupNorm stats =====
  {
    int gid = blk * 512 + t;
    if (gid < 24576) {                       // 98304 floats of qkv_w
      float4 f = ((const float4*)qkvw)[gid];
      ushort4 o;
      o.x = f2b(f.x); o.y = f2b(f.y); o.z = f2b(f.z); o.w = f2b(f.w);
      ((ushort4*)cqkvw)[gid] = o;
    } else if (gid < 24576 + 16896) {        // zero ctxg(65536)+sbuf(2048) floats
      ((float4*)ctxg)[gid - 24576] = make_float4(0.f, 0.f, 0.f, 0.f);
    }
    // stats: 2 groups per block, one per 256-thread half
    int half = t >> 8, tid = t & 255;
    int grp = blk * 2 + half;                // 0..511
    int b = grp >> 5, g = grp & 31;
    const float* p = x + ((size_t)b * C_ + g * 8) * HW_;
    float s = 0.f, sq = 0.f;
#pragma unroll
    for (int i = 0; i < 16; ++i) {
      float4 u0 = *(const float4*)(p + tid * 8 + i * 2048);
      float4 u1 = *(const float4*)(p + tid * 8 + i * 2048 + 4);
      s  += u0.x + u0.y + u0.z + u0.w + u1.x + u1.y + u1.z + u1.w;
      sq += u0.x*u0.x + u0.y*u0.y + u0.z*u0.z + u0.w*u0.w
          + u1.x*u1.x + u1.y*u1.y + u1.z*u1.z + u1.w*u1.w;
    }
#pragma unroll
    for (int off = 32; off > 0; off >>= 1) {
      s  += __shfl_down(s, off);
      sq += __shfl_down(sq, off);
    }
    float* ps = (float*)smem_raw;            // [8]
    float* pq = ps + 8;                      // [8]
    float* mrA = pq + 8;                     // [2][2]
    int lane = t & 63, w = t >> 6;           // w 0..7
    if (lane == 0) { ps[w] = s; pq[w] = sq; }
    __syncthreads();
    if (tid == 0) {
      float S = ps[half*4] + ps[half*4+1] + ps[half*4+2] + ps[half*4+3];
      float Q = pq[half*4] + pq[half*4+1] + pq[half*4+2] + pq[half*4+3];
      float mean = S * (1.f / 32768.f);
      float var  = Q * (1.f / 32768.f) - mean * mean;
      mrA[half*2]   = mean;
      mrA[half*2+1] = rsqrtf(var + 1e-5f);
    }
    __syncthreads();
    if (tid < 8) {
      int c = g * 8 + tid;
      float sc = gnw[c] * mrA[half*2+1];
      scale[b * C_ + c]  = sc;
      shiftv[b * C_ + c] = gnb[c] - mrA[half*2] * sc;
    }
  }
  grid_barrier(bar);

  // ===== Phase 1: GN-apply + transpose x -> xn_t[b][4096][256] bf16 =====
  {
    int sg = t >> 8, tid = t & 255;
#pragma unroll 1
    for (int iter = 0; iter < 4; ++iter) {
      int task = iter * 512 + blk * 2 + sg;  // 0..2047
      int nt = task & 31, ct = (task >> 5) & 3, b = task >> 7;
      const float* S = x + (size_t)b * C_ * HW_;
      u16* D = xn_t + (size_t)b * HW_ * C_;
      u16* tl = (u16*)smem_raw + sg * 8704;  // 64*136 u16 per subgroup
      int n0 = nt * 128, c0 = ct * 64;
      int r = tid >> 2, seg = (tid & 3) * 32;
      float sc = scale[(size_t)b * C_ + c0 + r];
      float sh = shiftv[(size_t)b * C_ + c0 + r];
#pragma unroll
      for (int i = 0; i < 4; ++i) {
        const float* rp = S + (size_t)(c0 + r) * HW_ + n0 + seg + i * 8;
        float4 u0 = *(const float4*)(rp);
        float4 u1 = *(const float4*)(rp + 4);
        float f[8] = {u0.x, u0.y, u0.z, u0.w, u1.x, u1.y, u1.z, u1.w};
        uint4 o;
        uint32_t* op = (uint32_t*)&o;
#pragma unroll
        for (int j = 0; j < 4; ++j)
          op[j] = (uint32_t)f2b(f[2*j] * sc + sh)
                | ((uint32_t)f2b(f[2*j+1] * sc + sh) << 16);
        *(uint4*)&tl[r * 136 + seg + i * 8] = o;
      }
      __syncthreads();
#pragma unroll
      for (int i = 0; i < 4; ++i) {
        int m = tid * 4 + i;
        int n_l = m >> 3, cg = (m & 7) * 8;
        union { u16 v[8]; uint4 q; } pk;
#pragma unroll
        for (int e = 0; e < 8; ++e) pk.v[e] = tl[(cg + e) * 136 + n_l];
        *(uint4*)(D + (size_t)(n0 + n_l) * C_ + c0 + cg) = pk.q;
      }
      __syncthreads();
    }
  }
  grid_barrier(bar);

  // ===== Phase 2: QKV GEMM, 128x256 tile, 512 threads, BK=64 =====
  // mt=0 (q): restage -> q_t[b][n][128]; mt=1,2 (k,v): kv[b][o-128][n].
  {
    u16* lA = (u16*)smem_raw;                // 128x64
    u16* lB = lA + 8192;                     // 256x64
    int lane = t & 63, w = t >> 6;
    int quad = lane >> 4, l16 = lane & 15;
    int wm = (w >> 2) * 64, wn = (w & 3) * 64;
#pragma unroll 1
    for (int iter = 0; iter < 3; ++iter) {
      int task = iter * 256 + blk;           // 0..767
      int b = task / 48, r48 = task % 48;
      int mt = r48 >> 4, nt = r48 & 15;
      const u16* Ab = cqkvw + (size_t)mt * 128 * 256;
      const u16* Bb = xn_t + (size_t)b * HW_ * C_ + (size_t)nt * 256 * 256;
      f32x4 acc[4][4];
#pragma unroll
      for (int i = 0; i < 4; ++i)
#pragma unroll
        for (int j = 0; j < 4; ++j)
#pragma unroll
          for (int r = 0; r < 4; ++r) acc[i][j][r] = 0.f;
      for (int k0 = 0; k0 < 256; k0 += 64) {
        __syncthreads();
#pragma unroll
        for (int q = 0; q < 6; ++q) {
          int ch = q * 512 + t;
          if (ch < 1024) {
            int row = ch >> 3, off = (ch & 7) * 8;
            __builtin_amdgcn_global_load_lds(
                (const __attribute__((address_space(1))) void*)(Ab + (size_t)row * 256 + k0 + off),
                (__attribute__((address_space(3))) void*)(lA + ch * 8), 16, 0, 0);
          } else {
            int c2 = ch - 1024;
            int row = c2 >> 3, off = (c2 & 7) * 8;
            __builtin_amdgcn_global_load_lds(
                (const __attribute__((address_space(1))) void*)(Bb + (size_t)row * 256 + k0 + off),
                (__attribute__((address_space(3))) void*)(lB + c2 * 8), 16, 0, 0);
          }
        }
        __syncthreads();
        const bf16x8* A8 = (const bf16x8*)lA;
        const bf16x8* B8 = (const bf16x8*)lB;
#pragma unroll
        for (int kk = 0; kk < 2; ++kk) {
          bf16x8 af[4], bfr[4];
#pragma unroll
          for (int i = 0; i < 4; ++i) af[i]  = A8[(wm + i * 16 + l16) * 8 + kk * 4 + quad];
#pragma unroll
          for (int j = 0; j < 4; ++j) bfr[j] = B8[(wn + j * 16 + l16) * 8 + kk * 4 + quad];
#pragma unroll
          for (int i = 0; i < 4; ++i)
#pragma unroll
            for (int j = 0; j < 4; ++j)
              acc[i][j] = __builtin_amdgcn_mfma_f32_16x16x32_bf16(af[i], bfr[j],
                                                                  acc[i][j], 0, 0, 0);
        }
      }
      __syncthreads();
      if (mt == 0) {
        u16* ot = (u16*)smem_raw;            // [n 256][o stride 136]
#pragma unroll
        for (int i = 0; i < 4; ++i) {
          int o0 = wm + i * 16 + quad * 4;
          float b0 = qkvb[o0], b1 = qkvb[o0+1], b2 = qkvb[o0+2], b3 = qkvb[o0+3];
#pragma unroll
          for (int j = 0; j < 4; ++j) {
            int n_l = wn + j * 16 + l16;
            uint2 pk;
            pk.x = (uint32_t)f2b(acc[i][j][0] + b0) | ((uint32_t)f2b(acc[i][j][1] + b1) << 16);
            pk.y = (uint32_t)f2b(acc[i][j][2] + b2) | ((uint32_t)f2b(acc[i][j][3] + b3) << 16);
            *(uint2*)&ot[n_l * 136 + o0] = pk;
          }
        }
      } else {
#pragma unroll
        for (int i = 0; i < 4; ++i) {
#pragma unroll
          for (int rg = 0; rg < 4; ++rg) {
            int o = mt * 128 + wm + i * 16 + quad * 4 + rg;
            float bsv = qkvb[o];
            u16* kr = kv + ((size_t)b * 256 + (o - 128)) * HW_;
#pragma unroll
            for (int j = 0; j < 4; ++j) {
              int n = nt * 256 + wn + j * 16 + l16;
              kr[n] = f2b(acc[i][j][rg] + bsv);
            }
          }
        }
      }
      __syncthreads();
      if (mt == 0) {
        int n_l = t >> 1, half = t & 1;
        u16* dst = q_t + (size_t)b * HW_ * HID_ + (size_t)(nt * 256 + n_l) * HID_ + half * 64;
        const u16* sp = (const u16*)smem_raw + n_l * 136 + half * 64;
#pragma unroll
        for (int i = 0; i < 8; ++i)
          *(uint4*)(dst + i * 8) = *(const uint4*)(sp + i * 8);
      }
    }
  }
  grid_barrier(bar);

  // ===== Phase 3: softmax-exp + partial context, atomics into ctxg/sbuf =====
  {
    int sg = t >> 8, tid = t & 255;
    int task = blk * 2 + sg;                 // 0..511 = (b,h,chunk8)
    int b = task >> 5, h = (task >> 3) & 3, chunk = task & 7;
    const u16* kb = kv + ((size_t)b * 256 + h * 32) * HW_;
    const u16* vb = kv + ((size_t)b * 256 + 128 + h * 32) * HW_;
    int wl = tid >> 6, lane = t & 63;
    int quad = lane >> 4, l16 = lane & 15;
    float* part = (float*)smem_raw + sg * 4608;  // [4][1024] + sred[4][128]
    float* sred = part + 4096;
    f32x4 acc[2][2];
#pragma unroll
    for (int i = 0; i < 2; ++i)
#pragma unroll
      for (int j = 0; j < 2; ++j)
#pragma unroll
        for (int r = 0; r < 4; ++r) acc[i][j][r] = 0.f;
    float s0 = 0.f, s1 = 0.f;
    int base = chunk * 512 + wl * 128;
#pragma unroll 1
    for (int it = 0; it < 4; ++it) {
      int n0 = base + it * 32 + quad * 8;
      bf16x8 k0 = *(const bf16x8*)(kb + (size_t)l16 * HW_ + n0);
      bf16x8 k1 = *(const bf16x8*)(kb + (size_t)(16 + l16) * HW_ + n0);
      bf16x8 v0 = *(const bf16x8*)(vb + (size_t)l16 * HW_ + n0);
      bf16x8 v1 = *(const bf16x8*)(vb + (size_t)(16 + l16) * HW_ + n0);
      bf16x8 a0, a1;
      const u16* k0p = (const u16*)&k0; u16* a0p = (u16*)&a0;
      const u16* k1p = (const u16*)&k1; u16* a1p = (u16*)&a1;
#pragma unroll
      for (int e = 0; e < 8; ++e) {
        float e0 = __expf(b2f(k0p[e]));
        float e1 = __expf(b2f(k1p[e]));
        s0 += e0; s1 += e1;
        a0p[e] = f2b(e0); a1p[e] = f2b(e1);
      }
      acc[0][0] = __builtin_amdgcn_mfma_f32_16x16x32_bf16(a0, v0, acc[0][0], 0, 0, 0);
      acc[0][1] = __builtin_amdgcn_mfma_f32_16x16x32_bf16(a0, v1, acc[0][1], 0, 0, 0);
      acc[1][0] = __builtin_amdgcn_mfma_f32_16x16x32_bf16(a1, v0, acc[1][0], 0, 0, 0);
      acc[1][1] = __builtin_amdgcn_mfma_f32_16x16x32_bf16(a1, v1, acc[1][1], 0, 0, 0);
    }
#pragma unroll
    for (int i = 0; i < 2; ++i)
#pragma unroll
      for (int j = 0; j < 2; ++j)
#pragma unroll
        for (int r = 0; r < 4; ++r) {
          int d = i * 16 + quad * 4 + r;
          int e = j * 16 + l16;
          part[wl * 1024 + d * 32 + e] = acc[i][j][r];
        }
    sred[wl * 128 + (lane & 63) * 2]     = s0;
    sred[wl * 128 + (lane & 63) * 2 + 1] = s1;
    __syncthreads();
    float* cb = ctxg + (size_t)(b * 4 + h) * 1024;
#pragma unroll
    for (int i = 0; i < 4; ++i) {
      int idx = tid + i * 256;
      atomicAdd(&cb[idx], part[idx] + part[1024 + idx] + part[2048 + idx] + part[3072 + idx]);
    }
    if (tid < 32) {
      int d = tid;
      float ss = 0.f;
#pragma unroll
      for (int w2 = 0; w2 < 4; ++w2)
#pragma unroll
        for (int q = 0; q < 4; ++q)
          ss += sred[w2 * 128 + (q * 16 + (d & 15)) * 2 + (d >> 4)];
      atomicAdd(&sbuf[(b * 4 + h) * 32 + d], ss);
    }
  }
  grid_barrier(bar);

  // ===== Phase 4: fold wf = (outw . ctx)/s in LDS, GEMM out = wf @ q_t^T =====
  {
    u16* wfA = (u16*)smem_raw;                         // [o 256][k stride 136]
    u16* lB  = (u16*)smem_raw + 256 * 136;             // [n 128][k 128]
    float* ctxs = (float*)(smem_raw + 69632 + 32768);  // 4096 floats
    float* sinv = (float*)(smem_raw + 69632 + 32768 + 16384); // 128
    int lane = t & 63, w = t >> 6;
    int quad = lane >> 4, l16 = lane & 15;
    int wm = (w >> 1) * 64, wn = (w & 1) * 64;
#pragma unroll 1
    for (int iter = 0; iter < 2; ++iter) {
      int task = iter * 256 + blk;           // 0..511
      int nt = task & 31, b = task >> 5;
      __syncthreads();
      {
        const float* cb = ctxg + (size_t)b * 4096;
#pragma unroll
        for (int i = 0; i < 8; ++i) ctxs[t + i * 512] = cb[t + i * 512];
        if (t < 128) sinv[t] = 1.f / sbuf[b * 128 + t];
      }
#pragma unroll
      for (int q = 0; q < 4; ++q) {
        int ch = q * 512 + t;
        int row = ch >> 4, off = (ch & 15) * 8;
        __builtin_amdgcn_global_load_lds(
            (const __attribute__((address_space(1))) void*)(q_t + ((size_t)b * HW_ + nt * 128 + row) * HID_ + off),
            (__attribute__((address_space(3))) void*)(lB + ch * 8), 16, 0, 0);
      }
      __syncthreads();
      {
        int o = t >> 1, half = t & 1;
        const float* wr = outw + (size_t)o * HID_ + half * 64;
        float wv[64];
#pragma unroll
        for (int e = 0; e < 64; ++e) wv[e] = wr[e];
        u16* dr = wfA + o * 136 + half * 64;
#pragma unroll
        for (int hh = 0; hh < 2; ++hh) {
          int h = half * 2 + hh;
#pragma unroll
          for (int d = 0; d < 32; d += 2) {
            float a0 = 0.f, a1 = 0.f;
#pragma unroll
            for (int e = 0; e < 32; ++e) {
              a0 += wv[hh * 32 + e] * ctxs[h * 1024 + d * 32 + e];
              a1 += wv[hh * 32 + e] * ctxs[h * 1024 + (d + 1) * 32 + e];
            }
            a0 *= sinv[half * 64 + hh * 32 + d];
            a1 *= sinv[half * 64 + hh * 32 + d + 1];
            *(uint32_t*)&dr[hh * 32 + d] = (uint32_t)f2b(a0) | ((uint32_t)f2b(a1) << 16);
          }
        }
      }
      __syncthreads();
      f32x4 acc[4][4];
#pragma unroll
      for (int i = 0; i < 4; ++i)
#pragma unroll
        for (int j = 0; j < 4; ++j)
#pragma unroll
          for (int r = 0; r < 4; ++r) acc[i][j][r] = 0.f;
      const bf16x8* A8 = (const bf16x8*)wfA;   // row stride 17 units
      const bf16x8* B8 = (const bf16x8*)lB;    // row stride 16 units
#pragma unroll
      for (int kk = 0; kk < 4; ++kk) {
        bf16x8 af[4], bfr[4];
#pragma unroll
        for (int i = 0; i < 4; ++i) af[i]  = A8[(wm + i * 16 + l16) * 17 + kk * 4 + quad];
#pragma unroll
        for (int j = 0; j < 4; ++j) bfr[j] = B8[(wn + j * 16 + l16) * 16 + kk * 4 + quad];
#pragma unroll
        for (int i = 0; i < 4; ++i)
#pragma unroll
          for (int j = 0; j < 4; ++j)
            acc[i][j] = __builtin_amdgcn_mfma_f32_16x16x32_bf16(af[i], bfr[j],
                                                                acc[i][j], 0, 0, 0);
      }
#pragma unroll
      for (int i = 0; i < 4; ++i) {
#pragma unroll
        for (int rg = 0; rg < 4; ++rg) {
          int o = wm + i * 16 + quad * 4 + rg;
          float bsv = outb[o];
          size_t rowb = ((size_t)b * C_ + o) * HW_;
#pragma unroll
          for (int j = 0; j < 4; ++j) {
            int n = nt * 128 + wn + j * 16 + l16;
            out[rowb + n] = acc[i][j][rg] + bsv;
          }
        }
      }
    }
  }
}

// ---------------------------------------------------------------------------
extern "C" void kernel_launch(void* const* d_in, const int* in_sizes, int n_in,
                              void* d_out, int out_size, void* d_ws, size_t ws_size,
                              hipStream_t stream)
{
  const float* x    = (const float*)d_in[0];
  const float* gnw  = (const float*)d_in[1];
  const float* gnb  = (const float*)d_in[2];
  const float* qkvw = (const float*)d_in[3];
  const float* qkvb = (const float*)d_in[4];
  const float* outw = (const float*)d_in[5];
  const float* outb = (const float*)d_in[6];
  float* out = (float*)d_out;

  char* p = (char*)d_ws;
  unsigned* bar = (unsigned*)p;         p += 128;
  float* scale  = (float*)p;            p += (size_t)B_ * C_ * 4;
  float* shiftv = (float*)p;            p += (size_t)B_ * C_ * 4;
  u16* cqkvw = (u16*)p;                 p += (size_t)384 * C_ * 2;
  float* ctxg = (float*)p;              p += (size_t)B_ * 4 * 1024 * 4;
  float* sbuf = (float*)p;              p += (size_t)B_ * 4 * 32 * 4;
  u16* xn_t  = (u16*)p;                 p += (size_t)B_ * HW_ * C_ * 2;
  u16* kv    = (u16*)p;                 p += (size_t)B_ * 256 * HW_ * 2;
  u16* q_t   = (u16*)p;

  init_kernel<<<1, 64, 0, stream>>>(bar);
  mega_kernel<<<NBLK, 512, 0, stream>>>(x, gnw, gnb, qkvw, qkvb, outw, outb, out,
                                        bar, scale, shiftv, cqkvw, xn_t, kv, q_t,
                                        ctxg, sbuf);
}

// Round 8
// 210.434 us; speedup vs baseline: 2.1355x; 2.1355x over previous
//
#include <hip/hip_runtime.h>
#include <stdint.h>

typedef unsigned short u16;
typedef __attribute__((ext_vector_type(8))) short bf16x8;   // 8 bf16 in 4 VGPRs
typedef __attribute__((ext_vector_type(4))) float f32x4;

#define B_   16
#define C_   256
#define HW_  4096
#define QR_  384
#define HID_ 128

__device__ __forceinline__ float b2f(u16 u) {
  union { uint32_t i; float f; } v; v.i = ((uint32_t)u) << 16; return v.f;
}
__device__ __forceinline__ u16 f2b(float f) {
  union { float f; uint32_t i; } v; v.f = f;
  uint32_t r = (v.i + 0x7FFFu + ((v.i >> 16) & 1u)) >> 16;
  return (u16)r;
}

// ---------------------------------------------------------------------------
// K1: heterogeneous: blocks [0,512) GroupNorm stats; blocks [512,608) convert
// qkv_w fp32 -> bf16.
// ---------------------------------------------------------------------------
__global__ __launch_bounds__(256) void gn_stats_conv_kernel(
    const float* __restrict__ x, const float* __restrict__ gnw,
    const float* __restrict__ gnb, float* __restrict__ scale,
    float* __restrict__ shiftv,
    const float* __restrict__ qkvw, u16* __restrict__ cqkvw)
{
  if (blockIdx.x >= 512) {
    int i = (blockIdx.x - 512) * 256 + threadIdx.x;   // < 24576 exactly
    float4 f = ((const float4*)qkvw)[i];
    ushort4 o;
    o.x = f2b(f.x); o.y = f2b(f.y); o.z = f2b(f.z); o.w = f2b(f.w);
    ((ushort4*)cqkvw)[i] = o;
    return;
  }
  int b = blockIdx.x >> 5, g = blockIdx.x & 31;
  const float* p = x + ((size_t)b * C_ + g * 8) * HW_;
  int t = threadIdx.x;
  float s = 0.f, sq = 0.f;
#pragma unroll
  for (int i = 0; i < 16; ++i) {
    float4 u0 = *(const float4*)(p + t * 8 + i * 2048);
    float4 u1 = *(const float4*)(p + t * 8 + i * 2048 + 4);
    s  += u0.x + u0.y + u0.z + u0.w + u1.x + u1.y + u1.z + u1.w;
    sq += u0.x*u0.x + u0.y*u0.y + u0.z*u0.z + u0.w*u0.w
        + u1.x*u1.x + u1.y*u1.y + u1.z*u1.z + u1.w*u1.w;
  }
#pragma unroll
  for (int off = 32; off > 0; off >>= 1) {
    s  += __shfl_down(s, off);
    sq += __shfl_down(sq, off);
  }
  __shared__ float ps[4], pq[4], mr[2];
  int lane = t & 63, w = t >> 6;
  if (lane == 0) { ps[w] = s; pq[w] = sq; }
  __syncthreads();
  if (t == 0) {
    float S = ps[0] + ps[1] + ps[2] + ps[3];
    float Q = pq[0] + pq[1] + pq[2] + pq[3];
    float mean = S * (1.f / 32768.f);
    float var  = Q * (1.f / 32768.f) - mean * mean;
    mr[0] = mean; mr[1] = rsqrtf(var + 1e-5f);
  }
  __syncthreads();
  if (t < 8) {
    int c = g * 8 + t;
    float sc = gnw[c] * mr[1];
    scale[b * C_ + c]  = sc;
    shiftv[b * C_ + c] = gnb[c] - mr[0] * sc;
  }
}

// ---------------------------------------------------------------------------
// K2: fused GN-apply + transpose: x fp32 [b][256][4096] -> xn_t bf16
// [b][4096][256]. tile 64 c x 128 n, grid (32, 4, 16).
// ---------------------------------------------------------------------------
__global__ __launch_bounds__(256) void gn_transpose_kernel(
    const float* __restrict__ x, u16* __restrict__ dst,
    const float* __restrict__ scale, const float* __restrict__ shiftv)
{
  int nt = blockIdx.x, ct = blockIdx.y, b = blockIdx.z;
  const float* S = x + (size_t)b * C_ * HW_;
  u16* D = dst + (size_t)b * HW_ * C_;
  __shared__ __align__(16) u16 tile[64][136];
  int t = threadIdx.x;
  int n0 = nt * 128, c0 = ct * 64;
  int r = t >> 2, seg = (t & 3) * 32;
  float sc = scale[(size_t)b * C_ + c0 + r];
  float sh = shiftv[(size_t)b * C_ + c0 + r];
#pragma unroll
  for (int i = 0; i < 4; ++i) {
    const float* rp = S + (size_t)(c0 + r) * HW_ + n0 + seg + i * 8;
    float4 u0 = *(const float4*)(rp);
    float4 u1 = *(const float4*)(rp + 4);
    float f[8] = {u0.x, u0.y, u0.z, u0.w, u1.x, u1.y, u1.z, u1.w};
    uint4 o;
    uint32_t* op = (uint32_t*)&o;
#pragma unroll
    for (int j = 0; j < 4; ++j) {
      op[j] = (uint32_t)f2b(f[2 * j] * sc + sh)
            | ((uint32_t)f2b(f[2 * j + 1] * sc + sh) << 16);
    }
    *(uint4*)&tile[r][seg + i * 8] = o;
  }
  __syncthreads();
#pragma unroll
  for (int i = 0; i < 4; ++i) {
    int m = t * 4 + i;
    int n_l = m >> 3, cg = (m & 7) * 8;
    union { u16 v[8]; uint4 q; } pk;
#pragma unroll
    for (int e = 0; e < 8; ++e) pk.v[e] = tile[cg + e][n_l];
    *(uint4*)(D + (size_t)(n0 + n_l) * C_ + c0 + cg) = pk.q;
  }
}

// ---------------------------------------------------------------------------
// K3: QKV GEMM. C = qkv_w(bf16) @ xn_t^T (+fp32 bias). 128x128 tile, BK=64,
// global_load_lds staging with XOR bank swizzle: global chunk
// (row, col^(row&7)) lands in LDS slot (row, col), so the MFMA fragment read
// (row, c) comes from slot (row, c^(row&7)) -> 2 lanes/bank (conflict-free)
// instead of 16-way conflicts at row-stride 128B.
// mt=0 (q): restage -> q_t[b][n][128]; mt=1,2 (k,v): qkv rows. grid (32,3,16).
// ---------------------------------------------------------------------------
__global__ __launch_bounds__(256) void qkv_gemm_kernel(
    const u16* __restrict__ A, const u16* __restrict__ Bt,
    const float* __restrict__ bias, u16* __restrict__ qkv,
    u16* __restrict__ q_t)
{
  const int K = C_;
  int nt = blockIdx.x, mt = blockIdx.y, b = blockIdx.z;
  const u16* Ab = A + (size_t)mt * 128 * K;
  const u16* Bb = Bt + (size_t)b * HW_ * C_ + (size_t)nt * 128 * K;
  __shared__ __align__(16) u16 smem[128 * 136];   // staging (2x8192) / out-tile
  u16* lA = smem;
  u16* lB = smem + 8192;
  int t = threadIdx.x;
  int lane = t & 63, w = t >> 6;
  int quad = lane >> 4, l16 = lane & 15;
  int wm = (w >> 1) * 64, wn = (w & 1) * 64;
  f32x4 acc[4][4];
#pragma unroll
  for (int i = 0; i < 4; ++i)
#pragma unroll
    for (int j = 0; j < 4; ++j)
#pragma unroll
      for (int r = 0; r < 4; ++r) acc[i][j][r] = 0.f;

  for (int k0 = 0; k0 < K; k0 += 64) {
    __syncthreads();
#pragma unroll
    for (int q = 0; q < 4; ++q) {
      int ch = q * 256 + t;             // 1024 x 16B chunks per operand
      int row = ch >> 3, col = ch & 7;
      int off = (col ^ (row & 7)) * 8;  // XOR swizzle (same 128B line)
      __builtin_amdgcn_global_load_lds(
          (const __attribute__((address_space(1))) void*)(Ab + (size_t)row * K + k0 + off),
          (__attribute__((address_space(3))) void*)(lA + ch * 8), 16, 0, 0);
      __builtin_amdgcn_global_load_lds(
          (const __attribute__((address_space(1))) void*)(Bb + (size_t)row * K + k0 + off),
          (__attribute__((address_space(3))) void*)(lB + ch * 8), 16, 0, 0);
    }
    __syncthreads();
    const bf16x8* A8 = (const bf16x8*)lA;
    const bf16x8* B8 = (const bf16x8*)lB;
#pragma unroll
    for (int kk = 0; kk < 2; ++kk) {
      bf16x8 af[4], bfr[4];
#pragma unroll
      for (int i = 0; i < 4; ++i) {
        int ar = wm + i * 16 + l16;
        af[i] = A8[ar * 8 + ((kk * 4 + quad) ^ (ar & 7))];
      }
#pragma unroll
      for (int j = 0; j < 4; ++j) {
        int br = wn + j * 16 + l16;
        bfr[j] = B8[br * 8 + ((kk * 4 + quad) ^ (br & 7))];
      }
#pragma unroll
      for (int i = 0; i < 4; ++i)
#pragma unroll
        for (int j = 0; j < 4; ++j)
          acc[i][j] = __builtin_amdgcn_mfma_f32_16x16x32_bf16(af[i], bfr[j],
                                                              acc[i][j], 0, 0, 0);
    }
  }

  if (mt == 0) {
    // q tile: restage transposed into LDS [n_local][o] (stride 136), write q_t.
    __syncthreads();
#pragma unroll
    for (int i = 0; i < 4; ++i) {
      int o0 = wm + i * 16 + quad * 4;
      float b0 = bias[o0], b1 = bias[o0 + 1], b2 = bias[o0 + 2], b3 = bias[o0 + 3];
#pragma unroll
      for (int j = 0; j < 4; ++j) {
        int n_l = wn + j * 16 + l16;
        uint2 pk;
        pk.x = (uint32_t)f2b(acc[i][j][0] + b0) | ((uint32_t)f2b(acc[i][j][1] + b1) << 16);
        pk.y = (uint32_t)f2b(acc[i][j][2] + b2) | ((uint32_t)f2b(acc[i][j][3] + b3) << 16);
        *(uint2*)&smem[n_l * 136 + o0] = pk;
      }
    }
    __syncthreads();
    int n_l = t >> 1, half = t & 1;
    u16* dst = q_t + (size_t)b * HW_ * HID_ + (size_t)(nt * 128 + n_l) * HID_ + half * 64;
    const u16* srcp = smem + n_l * 136 + half * 64;
#pragma unroll
    for (int i = 0; i < 8; ++i)
      *(uint4*)(dst + i * 8) = *(const uint4*)(srcp + i * 8);
  } else {
#pragma unroll
    for (int i = 0; i < 4; ++i) {
#pragma unroll
      for (int rg = 0; rg < 4; ++rg) {
        int o = mt * 128 + wm + i * 16 + quad * 4 + rg;
        float bsv = bias[o];
        size_t rowbase = (size_t)b * QR_ * HW_ + (size_t)o * HW_;
#pragma unroll
        for (int j = 0; j < 4; ++j) {
          int n = nt * 128 + wn + j * 16 + l16;
          qkv[rowbase + n] = f2b(acc[i][j][rg] + bsv);
        }
      }
    }
  }
}

// ---------------------------------------------------------------------------
// K4: single-pass fused softmax + context + weight-fold. grid 64 = (b,h),
// 1024 threads (16 waves). a = exp(k) (no max-sub; |k|<=~4), denominator s
// accumulated as by-product, applied as 1/s_d during the out_w fold.
// ---------------------------------------------------------------------------
__global__ __launch_bounds__(1024) void ctxwf_kernel(
    const u16* __restrict__ qkv, const float* __restrict__ outw,
    u16* __restrict__ wf)
{
  int b = blockIdx.x >> 2, h = blockIdx.x & 3;
  const u16* kb = qkv + ((size_t)b * QR_ + 128 + h * 32) * HW_;
  const u16* vb = qkv + ((size_t)b * QR_ + 256 + h * 32) * HW_;
  int t = threadIdx.x;
  int w = t >> 6, lane = t & 63;
  int quad = lane >> 4, l16 = lane & 15;
  __shared__ float part[16][1024];
  __shared__ float cs[1024];
  __shared__ float2 sred[1024];
  __shared__ float sinv[32];
  f32x4 acc[2][2];
#pragma unroll
  for (int i = 0; i < 2; ++i)
#pragma unroll
    for (int j = 0; j < 2; ++j)
#pragma unroll
      for (int r = 0; r < 4; ++r) acc[i][j][r] = 0.f;
  float s0 = 0.f, s1 = 0.f;
  int kbase = w * 256;
  for (int it = 0; it < 8; ++it) {
    int n0 = kbase + it * 32 + quad * 8;
    bf16x8 k0 = *(const bf16x8*)(kb + (size_t)l16 * HW_ + n0);
    bf16x8 k1 = *(const bf16x8*)(kb + (size_t)(16 + l16) * HW_ + n0);
    bf16x8 v0 = *(const bf16x8*)(vb + (size_t)l16 * HW_ + n0);
    bf16x8 v1 = *(const bf16x8*)(vb + (size_t)(16 + l16) * HW_ + n0);
    bf16x8 a0, a1;
    const u16* k0p = (const u16*)&k0; u16* a0p = (u16*)&a0;
    const u16* k1p = (const u16*)&k1; u16* a1p = (u16*)&a1;
#pragma unroll
    for (int e = 0; e < 8; ++e) {
      float e0 = __expf(b2f(k0p[e]));
      float e1 = __expf(b2f(k1p[e]));
      s0 += e0; s1 += e1;
      a0p[e] = f2b(e0);
      a1p[e] = f2b(e1);
    }
    acc[0][0] = __builtin_amdgcn_mfma_f32_16x16x32_bf16(a0, v0, acc[0][0], 0, 0, 0);
    acc[0][1] = __builtin_amdgcn_mfma_f32_16x16x32_bf16(a0, v1, acc[0][1], 0, 0, 0);
    acc[1][0] = __builtin_amdgcn_mfma_f32_16x16x32_bf16(a1, v0, acc[1][0], 0, 0, 0);
    acc[1][1] = __builtin_amdgcn_mfma_f32_16x16x32_bf16(a1, v1, acc[1][1], 0, 0, 0);
  }
#pragma unroll
  for (int i = 0; i < 2; ++i)
#pragma unroll
    for (int j = 0; j < 2; ++j)
#pragma unroll
      for (int r = 0; r < 4; ++r) {
        int d = i * 16 + quad * 4 + r;
        int e = j * 16 + l16;
        part[w][d * 32 + e] = acc[i][j][r];
      }
  sred[t] = make_float2(s0, s1);
  __syncthreads();
  {
    float a = 0.f;
#pragma unroll
    for (int ww = 0; ww < 16; ++ww) a += part[ww][t];
    cs[t] = a;
  }
  if (t < 32) {
    int d = t, lsel = d & 15;
    float ssum = 0.f;
#pragma unroll
    for (int ww = 0; ww < 16; ++ww)
#pragma unroll
      for (int q = 0; q < 4; ++q) {
        float2 v2 = sred[ww * 64 + q * 16 + lsel];
        ssum += (d < 16) ? v2.x : v2.y;
      }
    sinv[d] = 1.f / ssum;
  }
  __syncthreads();

  // ---- weight fold: thread (o = t&255, dg = t>>8) computes 8 outputs.
  int o = t & 255, dg = t >> 8;
  const float* wr = outw + (size_t)o * HID_ + h * 32;
  float wv[32];
#pragma unroll
  for (int e = 0; e < 32; ++e) wv[e] = wr[e];
  union { u16 v[8]; uint4 q; } pk;
#pragma unroll
  for (int dd = 0; dd < 8; ++dd) {
    int d = dg * 8 + dd;
    float a = 0.f;
#pragma unroll
    for (int e = 0; e < 32; ++e) a += wv[e] * cs[d * 32 + e];
    pk.v[dd] = f2b(a * sinv[d]);
  }
  *(uint4*)(wf + ((size_t)b * C_ + o) * HID_ + h * 32 + dg * 8) = pk.q;
}

// ---------------------------------------------------------------------------
// K5: final GEMM. out = wf(bf16 256x128) @ q_t^T (+outb), fp32 out.
// 128x128 tile, BK=64, K=128. Same XOR bank swizzle. grid (32, 2, 16).
// ---------------------------------------------------------------------------
__global__ __launch_bounds__(256) void out_gemm_kernel(
    const u16* __restrict__ A, const u16* __restrict__ Bt,
    const float* __restrict__ bias, float* __restrict__ Cout)
{
  const int K = HID_;
  int nt = blockIdx.x, mt = blockIdx.y, b = blockIdx.z;
  const u16* Ab = A + (size_t)b * C_ * HID_ + (size_t)mt * 128 * K;
  const u16* Bb = Bt + (size_t)b * HW_ * HID_ + (size_t)nt * 128 * K;
  __shared__ __align__(16) u16 lA[128 * 64];
  __shared__ __align__(16) u16 lB[128 * 64];
  int t = threadIdx.x;
  int lane = t & 63, w = t >> 6;
  int quad = lane >> 4, l16 = lane & 15;
  int wm = (w >> 1) * 64, wn = (w & 1) * 64;
  f32x4 acc[4][4];
#pragma unroll
  for (int i = 0; i < 4; ++i)
#pragma unroll
    for (int j = 0; j < 4; ++j)
#pragma unroll
      for (int r = 0; r < 4; ++r) acc[i][j][r] = 0.f;

  for (int k0 = 0; k0 < K; k0 += 64) {
    __syncthreads();
#pragma unroll
    for (int q = 0; q < 4; ++q) {
      int ch = q * 256 + t;
      int row = ch >> 3, col = ch & 7;
      int off = (col ^ (row & 7)) * 8;  // XOR swizzle
      __builtin_amdgcn_global_load_lds(
          (const __attribute__((address_space(1))) void*)(Ab + (size_t)row * K + k0 + off),
          (__attribute__((address_space(3))) void*)(lA + ch * 8), 16, 0, 0);
      __builtin_amdgcn_global_load_lds(
          (const __attribute__((address_space(1))) void*)(Bb + (size_t)row * K + k0 + off),
          (__attribute__((address_space(3))) void*)(lB + ch * 8), 16, 0, 0);
    }
    __syncthreads();
    const bf16x8* A8 = (const bf16x8*)lA;
    const bf16x8* B8 = (const bf16x8*)lB;
#pragma unroll
    for (int kk = 0; kk < 2; ++kk) {
      bf16x8 af[4], bfr[4];
#pragma unroll
      for (int i = 0; i < 4; ++i) {
        int ar = wm + i * 16 + l16;
        af[i] = A8[ar * 8 + ((kk * 4 + quad) ^ (ar & 7))];
      }
#pragma unroll
      for (int j = 0; j < 4; ++j) {
        int br = wn + j * 16 + l16;
        bfr[j] = B8[br * 8 + ((kk * 4 + quad) ^ (br & 7))];
      }
#pragma unroll
      for (int i = 0; i < 4; ++i)
#pragma unroll
        for (int j = 0; j < 4; ++j)
          acc[i][j] = __builtin_amdgcn_mfma_f32_16x16x32_bf16(af[i], bfr[j],
                                                              acc[i][j], 0, 0, 0);
    }
  }
#pragma unroll
  for (int i = 0; i < 4; ++i) {
#pragma unroll
    for (int rg = 0; rg < 4; ++rg) {
      int o = mt * 128 + wm + i * 16 + quad * 4 + rg;
      float bsv = bias[o];
      size_t rowbase = (size_t)b * C_ * HW_ + (size_t)o * HW_;
#pragma unroll
      for (int j = 0; j < 4; ++j) {
        int n = nt * 128 + wn + j * 16 + l16;
        Cout[rowbase + n] = acc[i][j][rg] + bsv;
      }
    }
  }
}

// ---------------------------------------------------------------------------
extern "C" void kernel_launch(void* const* d_in, const int* in_sizes, int n_in,
                              void* d_out, int out_size, void* d_ws, size_t ws_size,
                              hipStream_t stream)
{
  const float* x    = (const float*)d_in[0];
  const float* gnw  = (const float*)d_in[1];
  const float* gnb  = (const float*)d_in[2];
  const float* qkvw = (const float*)d_in[3];
  const float* qkvb = (const float*)d_in[4];
  const float* outw = (const float*)d_in[5];
  const float* outb = (const float*)d_in[6];

  char* p = (char*)d_ws;
  float* scale  = (float*)p;            p += (size_t)B_ * C_ * 4;
  float* shiftv = (float*)p;            p += (size_t)B_ * C_ * 4;
  u16* cqkvw = (u16*)p;                 p += (size_t)QR_ * C_ * 2;
  u16* xn_t  = (u16*)p;                 p += (size_t)B_ * HW_ * C_ * 2;
  u16* qkv   = (u16*)p;                 p += (size_t)B_ * QR_ * HW_ * 2;
  u16* q_t   = (u16*)p;                 p += (size_t)B_ * HW_ * HID_ * 2;
  u16* wf    = (u16*)p;

  gn_stats_conv_kernel<<<608, 256, 0, stream>>>(x, gnw, gnb, scale, shiftv,
                                                qkvw, cqkvw);
  gn_transpose_kernel<<<dim3(32, 4, 16), 256, 0, stream>>>(x, xn_t, scale, shiftv);
  qkv_gemm_kernel<<<dim3(32, 3, 16), 256, 0, stream>>>(cqkvw, xn_t, qkvb, qkv, q_t);
  ctxwf_kernel<<<64, 1024, 0, stream>>>(qkv, outw, wf);
  out_gemm_kernel<<<dim3(32, 2, 16), 256, 0, stream>>>(wf, q_t, outb, (float*)d_out);
}